// Round 9
// baseline (233.248 us; speedup 1.0000x reference)
//
#include <hip/hip_runtime.h>
#include <hip/hip_bf16.h>

#define B_SZ 1024
#define F_SZ 2048
#define NK   32
#define NCOL 256            // NK*KD
#define OUTF 2080           // F + NK
#define REP  8              // instrumentation multiplier (deterministic re-compute)

typedef __attribute__((ext_vector_type(8))) short short8v;
typedef __attribute__((ext_vector_type(4))) float f32x4;

static __device__ __forceinline__ unsigned short f2bf(float v) {
  __hip_bfloat16 h = __float2bfloat16(v);   // RNE
  return reinterpret_cast<unsigned short&>(h);
}

// ---------------------------------------------------------------------------
// ge: R5-style barrier-free GEMM, x8 reps.  m = x . W  (bf16 MFMA)
// 256 blocks x 512 thr; 32x32 tile; 8 waves split K; direct global->reg loads
// (A coalesced f32, B strided dword gather).  One __syncthreads per rep.
// ---------------------------------------------------------------------------
__global__ __launch_bounds__(512) void ge_gemm(
    const float* __restrict__ x, const float* __restrict__ W,
    float* __restrict__ m) {
  __shared__ float red[8][16][64];   // 32 KB

  int bid = blockIdx.x;
  int mt = bid & 31, nt = bid >> 5;
  int i0 = mt * 32, n0 = nt * 32;

  int t = threadIdx.x;
  int w = t >> 6, l = t & 63;
  int hi = l >> 4, r16 = l & 15;
  int hi8 = hi * 8;

  for (int rep = 0; rep < REP; ++rep) {
    f32x4 acc[2][2];
#pragma unroll
    for (int mi = 0; mi < 2; ++mi)
#pragma unroll
      for (int ni = 0; ni < 2; ++ni) acc[mi][ni] = (f32x4)(0.f);

    for (int ks = 0; ks < 8; ++ks) {   // wave-private K chunk, no barriers
      int kc = w * 256 + ks * 32;

      short8v af[2];
#pragma unroll
      for (int mi = 0; mi < 2; ++mi) {
        const float* ap = &x[(size_t)(i0 + mi * 16 + r16) * F_SZ + kc + hi8];
        float4 v0 = *reinterpret_cast<const float4*>(ap);
        float4 v1 = *reinterpret_cast<const float4*>(ap + 4);
        af[mi][0] = (short)f2bf(v0.x); af[mi][1] = (short)f2bf(v0.y);
        af[mi][2] = (short)f2bf(v0.z); af[mi][3] = (short)f2bf(v0.w);
        af[mi][4] = (short)f2bf(v1.x); af[mi][5] = (short)f2bf(v1.y);
        af[mi][6] = (short)f2bf(v1.z); af[mi][7] = (short)f2bf(v1.w);
      }

      short8v bfr[2];
#pragma unroll
      for (int ni = 0; ni < 2; ++ni) {
        int n = n0 + ni * 16 + r16;
        float wv[8];
#pragma unroll
        for (int u = 0; u < 8; ++u)
          wv[u] = W[(size_t)(kc + hi8 + u) * NCOL + n];
#pragma unroll
        for (int u = 0; u < 8; ++u) bfr[ni][u] = (short)f2bf(wv[u]);
      }

#pragma unroll
      for (int mi = 0; mi < 2; ++mi)
#pragma unroll
        for (int ni = 0; ni < 2; ++ni)
          acc[mi][ni] = __builtin_amdgcn_mfma_f32_16x16x32_bf16(
              af[mi], bfr[ni], acc[mi][ni], 0, 0, 0);
    }

#pragma unroll
    for (int mi = 0; mi < 2; ++mi)
#pragma unroll
      for (int ni = 0; ni < 2; ++ni)
#pragma unroll
        for (int r = 0; r < 4; ++r)
          red[w][mi * 8 + ni * 4 + r][l] = acc[mi][ni][r];
    __syncthreads();

#pragma unroll
    for (int s = 0; s < 2; ++s) {
      int slot = t + s * 512;
      int reg = slot >> 6, lane = slot & 63;
      float v = 0.f;
#pragma unroll
      for (int ww = 0; ww < 8; ++ww) v += red[ww][reg][lane];
      int mi = reg >> 3, ni = (reg >> 2) & 1, r = reg & 3;
      int row = i0 + mi * 16 + (lane >> 4) * 4 + r;
      int col = n0 + ni * 16 + (lane & 15);
      m[(size_t)row * NCOL + col] = v;
    }
    __syncthreads();   // red reuse across reps
  }
}

// ---------------------------------------------------------------------------
// cp: x -> out[:, 0:2048] copy, x8 reps.  256 blocks x 256 thr.
// ---------------------------------------------------------------------------
__global__ __launch_bounds__(256) void cp_copy(
    const float* __restrict__ x, float* __restrict__ out) {
  const float4* x4 = reinterpret_cast<const float4*>(x);
  int t = threadIdx.x, bid = blockIdx.x;
  for (int rep = 0; rep < REP; ++rep) {
    int idx = bid * 256 + t;
#pragma unroll
    for (int it = 0; it < 8; ++it, idx += 256 * 256) {
      int i  = idx >> 9;
      int c4 = idx & 511;
      *reinterpret_cast<float4*>(&out[(size_t)i * OUTF + c4 * 4]) = x4[idx];
    }
  }
}

// ---------------------------------------------------------------------------
// pw: pairwise L1+exp, x8 reps.  256 blocks x 1024 thr (R8 structure).
// ---------------------------------------------------------------------------
__global__ __launch_bounds__(1024) void pw_pairwise(
    const float* __restrict__ m, float* __restrict__ out) {
  __shared__ float red[32][4][33];

  int bid = blockIdx.x;
  int t = threadIdx.x;
  int k  = t & 31;
  int jc = t >> 5;
  int i0 = bid * 4;
  int j0 = jc * 32;

  const float4* mv = reinterpret_cast<const float4*>(m);

  for (int rep = 0; rep < REP; ++rep) {
    float4 a0[4], a1[4];
#pragma unroll
    for (int r = 0; r < 4; ++r) {
      a0[r] = mv[(size_t)(i0 + r) * 64 + k * 2];
      a1[r] = mv[(size_t)(i0 + r) * 64 + k * 2 + 1];
    }

    float acc[4] = {0.f, 0.f, 0.f, 0.f};
#pragma unroll 2
    for (int jj = 0; jj < 32; ++jj) {
      int j = j0 + jj;
      float4 c0 = mv[(size_t)j * 64 + k * 2];
      float4 c1 = mv[(size_t)j * 64 + k * 2 + 1];
#pragma unroll
      for (int r = 0; r < 4; ++r) {
        float s = fabsf(a0[r].x - c0.x) + fabsf(a0[r].y - c0.y) +
                  fabsf(a0[r].z - c0.z) + fabsf(a0[r].w - c0.w) +
                  fabsf(a1[r].x - c1.x) + fabsf(a1[r].y - c1.y) +
                  fabsf(a1[r].z - c1.z) + fabsf(a1[r].w - c1.w);
        acc[r] += __expf(-s);
      }
    }

#pragma unroll
    for (int r = 0; r < 4; ++r) red[jc][r][k] = acc[r];
    __syncthreads();

    if (t < 128) {
      int r = t >> 5, kk = t & 31;
      float s = 0.f;
#pragma unroll
      for (int c = 0; c < 32; ++c) s += red[c][r][kk];
      out[(size_t)(i0 + r) * OUTF + F_SZ + kk] = s;
    }
    __syncthreads();   // red reuse across reps
  }
}

extern "C" void kernel_launch(void* const* d_in, const int* in_sizes, int n_in,
                              void* d_out, int out_size, void* d_ws, size_t ws_size,
                              hipStream_t stream) {
  const float* x = (const float*)d_in[0];
  const float* W = (const float*)d_in[1];
  float* out = (float*)d_out;
  float* m = (float*)d_ws;    // 1 MB

  ge_gemm<<<dim3(256), 512, 0, stream>>>(x, W, m);
  cp_copy<<<dim3(256), 256, 0, stream>>>(x, out);
  pw_pairwise<<<dim3(256), 1024, 0, stream>>>(m, out);
}

// Round 11
// 69.095 us; speedup vs baseline: 3.3758x; 3.3758x over previous
//
#include <hip/hip_runtime.h>
#include <hip/hip_bf16.h>

#define B_SZ 1024
#define F_SZ 2048
#define NK   32
#define NCOL 256            // NK*KD
#define OUTF 2080           // F + NK

typedef __attribute__((ext_vector_type(8))) short short8v;
typedef __attribute__((ext_vector_type(4))) float f32x4;

static __device__ __forceinline__ unsigned short f2bf(float v) {
  __hip_bfloat16 h = __float2bfloat16(v);   // RNE
  return reinterpret_cast<unsigned short&>(h);
}

// ---------------------------------------------------------------------------
// K1: role-split 384 blocks x 512 thr.
//   bid 0..255   : R9-proven barrier-free GEMM (32x32 tile, 8 waves split K,
//                  direct global->reg, ~5.5 us cold).  m = x.W bf16 MFMA.
//   bid 256..383 : copy x rows into out[:, 0:2048] (co-resident; GEMM is
//                  latency-bound, copy is BW-bound -> they overlap).
// ---------------------------------------------------------------------------
__global__ __launch_bounds__(512) void k1_gemm_copy(
    const float* __restrict__ x, const float* __restrict__ W,
    float* __restrict__ m, float* __restrict__ out) {
  __shared__ float red[8][16][64];   // 32 KB

  int bid = blockIdx.x;
  int t = threadIdx.x;

  if (bid >= 256) {
    const float4* x4 = reinterpret_cast<const float4*>(x);
    int idx = (bid - 256) * 512 + t;
#pragma unroll
    for (int it = 0; it < 8; ++it, idx += 128 * 512) {
      int i  = idx >> 9;
      int c4 = idx & 511;
      *reinterpret_cast<float4*>(&out[(size_t)i * OUTF + c4 * 4]) = x4[idx];
    }
    return;
  }

  int mt = bid & 31, nt = bid >> 5;
  int i0 = mt * 32, n0 = nt * 32;
  int w = t >> 6, l = t & 63;
  int hi = l >> 4, r16 = l & 15;
  int hi8 = hi * 8;

  f32x4 acc[2][2];
#pragma unroll
  for (int mi = 0; mi < 2; ++mi)
#pragma unroll
    for (int ni = 0; ni < 2; ++ni) acc[mi][ni] = (f32x4)(0.f);

  for (int ks = 0; ks < 8; ++ks) {   // wave-private K chunk, no barriers
    int kc = w * 256 + ks * 32;

    short8v af[2];
#pragma unroll
    for (int mi = 0; mi < 2; ++mi) {
      const float* ap = &x[(size_t)(i0 + mi * 16 + r16) * F_SZ + kc + hi8];
      float4 v0 = *reinterpret_cast<const float4*>(ap);
      float4 v1 = *reinterpret_cast<const float4*>(ap + 4);
      af[mi][0] = (short)f2bf(v0.x); af[mi][1] = (short)f2bf(v0.y);
      af[mi][2] = (short)f2bf(v0.z); af[mi][3] = (short)f2bf(v0.w);
      af[mi][4] = (short)f2bf(v1.x); af[mi][5] = (short)f2bf(v1.y);
      af[mi][6] = (short)f2bf(v1.z); af[mi][7] = (short)f2bf(v1.w);
    }

    short8v bfr[2];
#pragma unroll
    for (int ni = 0; ni < 2; ++ni) {
      int n = n0 + ni * 16 + r16;
      float wv[8];
#pragma unroll
      for (int u = 0; u < 8; ++u)
        wv[u] = W[(size_t)(kc + hi8 + u) * NCOL + n];
#pragma unroll
      for (int u = 0; u < 8; ++u) bfr[ni][u] = (short)f2bf(wv[u]);
    }

#pragma unroll
    for (int mi = 0; mi < 2; ++mi)
#pragma unroll
      for (int ni = 0; ni < 2; ++ni)
        acc[mi][ni] = __builtin_amdgcn_mfma_f32_16x16x32_bf16(
            af[mi], bfr[ni], acc[mi][ni], 0, 0, 0);
  }

#pragma unroll
  for (int mi = 0; mi < 2; ++mi)
#pragma unroll
    for (int ni = 0; ni < 2; ++ni)
#pragma unroll
      for (int r = 0; r < 4; ++r)
        red[w][mi * 8 + ni * 4 + r][l] = acc[mi][ni][r];
  __syncthreads();

#pragma unroll
  for (int s = 0; s < 2; ++s) {
    int slot = t + s * 512;
    int reg = slot >> 6, lane = slot & 63;
    float v = 0.f;
#pragma unroll
    for (int ww = 0; ww < 8; ++ww) v += red[ww][reg][lane];
    int mi = reg >> 3, ni = (reg >> 2) & 1, r = reg & 3;
    int row = i0 + mi * 16 + (lane >> 4) * 4 + r;   // C/D: col=lane&15, row=(lane>>4)*4+reg
    int col = n0 + ni * 16 + (lane & 15);
    m[(size_t)row * NCOL + col] = v;
  }
}

// ---------------------------------------------------------------------------
// K2: SYMMETRIC pairwise.  528 blocks (tile-pairs (a,c), 0<=a<=c<=31 of 32-row
// tiles) x 512 thr.  Thread (ig=t&15, k=t>>4) owns 2 i-rows of tile a,
// loops 32 j of tile c with stagger jr=(jj+2*ig)&31:
//   - i-side: register accumulate (exact rows owned by this thread)
//   - j-side (a!=c): accJ[jr][k] += e0+e1 in LDS.  Race-free: all 16 threads
//     of a k-column are in ONE wave (lockstep) and stagger makes jr distinct
//     per instruction.
// Writes deterministic partials P[a][c][row][k] (i-side) / P[c][a][..] (j-side);
// each slot written exactly once.  Work = 0.52x of full pairwise.
// R10 FIX: accJ has 32*33=1056 floats; old init covered only 1024 -> rows
// jr=31,k>=1 started with garbage (absmax 6.16).  Full strided init now.
// ---------------------------------------------------------------------------
__global__ __launch_bounds__(512) void k2_sym_pairwise(
    const float* __restrict__ m, float* __restrict__ P) {
  __shared__ float accJ[32][33];

  int b = blockIdx.x;
  int a = 0, rem = b;
  while (rem >= 32 - a) { rem -= 32 - a; ++a; }   // triangular decode
  int c = a + rem;
  bool offd = (a != c);

  int t = threadIdx.x;
  int ig = t & 15, k = t >> 4;

  // init ALL of accJ (1056 floats)
  for (int e = t; e < 32 * 33; e += 512) ((float*)accJ)[e] = 0.f;
  __syncthreads();

  const float4* mv = reinterpret_cast<const float4*>(m);
  int ia = a * 32 + ig * 2;
  float4 A00 = mv[(size_t)ia * 64 + k * 2];
  float4 A01 = mv[(size_t)ia * 64 + k * 2 + 1];
  float4 A10 = mv[(size_t)(ia + 1) * 64 + k * 2];
  float4 A11 = mv[(size_t)(ia + 1) * 64 + k * 2 + 1];

  float accI0 = 0.f, accI1 = 0.f;
#pragma unroll 2
  for (int jj = 0; jj < 32; ++jj) {
    int jr = (jj + 2 * ig) & 31;
    int j = c * 32 + jr;
    float4 C0 = mv[(size_t)j * 64 + k * 2];
    float4 C1 = mv[(size_t)j * 64 + k * 2 + 1];
    float s0 = fabsf(A00.x - C0.x) + fabsf(A00.y - C0.y) +
               fabsf(A00.z - C0.z) + fabsf(A00.w - C0.w) +
               fabsf(A01.x - C1.x) + fabsf(A01.y - C1.y) +
               fabsf(A01.z - C1.z) + fabsf(A01.w - C1.w);
    float s1 = fabsf(A10.x - C0.x) + fabsf(A10.y - C0.y) +
               fabsf(A10.z - C0.z) + fabsf(A10.w - C0.w) +
               fabsf(A11.x - C1.x) + fabsf(A11.y - C1.y) +
               fabsf(A11.z - C1.z) + fabsf(A11.w - C1.w);
    float e0 = __expf(-s0);
    float e1 = __expf(-s1);
    accI0 += e0;
    accI1 += e1;
    if (offd) accJ[jr][k] += e0 + e1;   // lockstep wave, distinct (jr,k) per lane
  }

  // i-side partial: P[a][c][row][k]
  P[(((size_t)a * 32 + c) * 32 + ig * 2)     * 32 + k] = accI0;
  P[(((size_t)a * 32 + c) * 32 + ig * 2 + 1) * 32 + k] = accI1;

  if (offd) {
    __syncthreads();   // all waves' accJ RMW done
#pragma unroll
    for (int s = 0; s < 2; ++s) {
      int e = t + s * 512;           // 1024 elems
      int jr = e >> 5, kk = e & 31;
      P[(((size_t)c * 32 + a) * 32 + jr) * 32 + kk] = accJ[jr][kk];
    }
  }
}

// ---------------------------------------------------------------------------
// K3: finalize.  out[i][2048+k] = sum_{slot=0..31} P[i>>5][slot][i&31][k]
// 128 blocks x 256 thr (32768 outputs).  P is 4MB, L2-resident.
// ---------------------------------------------------------------------------
__global__ __launch_bounds__(256) void k3_finalize(
    const float* __restrict__ P, float* __restrict__ out) {
  int g = blockIdx.x * 256 + threadIdx.x;
  int i = g >> 5, k = g & 31;
  int aa = i >> 5, ir = i & 31;
  float s = 0.f;
#pragma unroll
  for (int sl = 0; sl < 32; ++sl)
    s += P[(((size_t)aa * 32 + sl) * 32 + ir) * 32 + k];
  out[(size_t)i * OUTF + F_SZ + k] = s;
}

extern "C" void kernel_launch(void* const* d_in, const int* in_sizes, int n_in,
                              void* d_out, int out_size, void* d_ws, size_t ws_size,
                              hipStream_t stream) {
  const float* x = (const float*)d_in[0];
  const float* W = (const float*)d_in[1];
  float* out = (float*)d_out;
  char* ws = (char*)d_ws;

  const size_t MB = 1u << 20;
  float* m = (float*)ws;              // 1 MB
  float* P = (float*)(ws + MB);       // 4 MB partials

  k1_gemm_copy<<<dim3(384), 512, 0, stream>>>(x, W, m, out);
  k2_sym_pairwise<<<dim3(528), 512, 0, stream>>>(m, P);
  k3_finalize<<<dim3(128), 256, 0, stream>>>(P, out);
}

// Round 12
// 38.866 us; speedup vs baseline: 6.0013x; 1.7778x over previous
//
#include <hip/hip_runtime.h>
#include <hip/hip_bf16.h>

#define B_SZ 1024
#define F_SZ 2048
#define NK   32
#define NCOL 256            // NK*KD
#define OUTF 2080           // F + NK

typedef __attribute__((ext_vector_type(8))) short short8v;
typedef __attribute__((ext_vector_type(4))) float f32x4;

static __device__ __forceinline__ unsigned short f2bf(float v) {
  __hip_bfloat16 h = __float2bfloat16(v);   // RNE
  return reinterpret_cast<unsigned short&>(h);
}

// ---------------------------------------------------------------------------
// K1: role-split 384 blocks x 512 thr.
//   bid 0..255   : R9-proven barrier-free GEMM (32x32 tile, 8 waves split K,
//                  direct global->reg).  m = x.W bf16 MFMA.  ~5.5 us.
//   bid 256..383 : copy x rows into out[:, 0:2048] AND zero out[:, 2048:2080]
//                  (K2 accumulates into it with atomics after the kernel
//                  boundary -- the only legal device-wide sync, R3/R7 lesson).
// ---------------------------------------------------------------------------
__global__ __launch_bounds__(512) void k1_gemm_copy(
    const float* __restrict__ x, const float* __restrict__ W,
    float* __restrict__ m, float* __restrict__ out) {
  __shared__ float red[8][16][64];   // 32 KB

  int bid = blockIdx.x;
  int t = threadIdx.x;

  if (bid >= 256) {
    const float4* x4 = reinterpret_cast<const float4*>(x);
    int idx = (bid - 256) * 512 + t;
    // zero the mb columns (32768 floats; half the copy threads)
    if (idx < B_SZ * NK)
      out[(size_t)(idx >> 5) * OUTF + F_SZ + (idx & 31)] = 0.f;
#pragma unroll
    for (int it = 0; it < 8; ++it, idx += 128 * 512) {
      int i  = idx >> 9;
      int c4 = idx & 511;
      *reinterpret_cast<float4*>(&out[(size_t)i * OUTF + c4 * 4]) = x4[(bid - 256) * 512 + t + it * 128 * 512];
    }
    return;
  }

  int mt = bid & 31, nt = bid >> 5;
  int i0 = mt * 32, n0 = nt * 32;
  int w = t >> 6, l = t & 63;
  int hi = l >> 4, r16 = l & 15;
  int hi8 = hi * 8;

  f32x4 acc[2][2];
#pragma unroll
  for (int mi = 0; mi < 2; ++mi)
#pragma unroll
    for (int ni = 0; ni < 2; ++ni) acc[mi][ni] = (f32x4)(0.f);

  for (int ks = 0; ks < 8; ++ks) {   // wave-private K chunk, no barriers
    int kc = w * 256 + ks * 32;

    short8v af[2];
#pragma unroll
    for (int mi = 0; mi < 2; ++mi) {
      const float* ap = &x[(size_t)(i0 + mi * 16 + r16) * F_SZ + kc + hi8];
      float4 v0 = *reinterpret_cast<const float4*>(ap);
      float4 v1 = *reinterpret_cast<const float4*>(ap + 4);
      af[mi][0] = (short)f2bf(v0.x); af[mi][1] = (short)f2bf(v0.y);
      af[mi][2] = (short)f2bf(v0.z); af[mi][3] = (short)f2bf(v0.w);
      af[mi][4] = (short)f2bf(v1.x); af[mi][5] = (short)f2bf(v1.y);
      af[mi][6] = (short)f2bf(v1.z); af[mi][7] = (short)f2bf(v1.w);
    }

    short8v bfr[2];
#pragma unroll
    for (int ni = 0; ni < 2; ++ni) {
      int n = n0 + ni * 16 + r16;
      float wv[8];
#pragma unroll
      for (int u = 0; u < 8; ++u)
        wv[u] = W[(size_t)(kc + hi8 + u) * NCOL + n];
#pragma unroll
      for (int u = 0; u < 8; ++u) bfr[ni][u] = (short)f2bf(wv[u]);
    }

#pragma unroll
    for (int mi = 0; mi < 2; ++mi)
#pragma unroll
      for (int ni = 0; ni < 2; ++ni)
        acc[mi][ni] = __builtin_amdgcn_mfma_f32_16x16x32_bf16(
            af[mi], bfr[ni], acc[mi][ni], 0, 0, 0);
  }

#pragma unroll
  for (int mi = 0; mi < 2; ++mi)
#pragma unroll
    for (int ni = 0; ni < 2; ++ni)
#pragma unroll
      for (int r = 0; r < 4; ++r)
        red[w][mi * 8 + ni * 4 + r][l] = acc[mi][ni][r];
  __syncthreads();

#pragma unroll
  for (int s = 0; s < 2; ++s) {
    int slot = t + s * 512;
    int reg = slot >> 6, lane = slot & 63;
    float v = 0.f;
#pragma unroll
    for (int ww = 0; ww < 8; ++ww) v += red[ww][reg][lane];
    int mi = reg >> 3, ni = (reg >> 2) & 1, r = reg & 3;
    int row = i0 + mi * 16 + (lane >> 4) * 4 + r;   // C/D: col=lane&15, row=(lane>>4)*4+reg
    int col = n0 + ni * 16 + (lane & 15);
    m[(size_t)row * NCOL + col] = v;
  }
}

// ---------------------------------------------------------------------------
// K2: symmetric pairwise, register j-side, R9-coalesced loads.
// 528 blocks (tile-pairs (a,c), 0<=a<=c<=31) x 512 thr.
// Thread (k=t&31, g=t>>5): owns i-rows {a*32+2g, +1}; loops j=c*32+jj with
// NO stagger -- all half-waves read the same 1KB m-row (coalesced, L1
// broadcast).  j-side partials live in accJr[32] REGISTERS (jj is a
// compile-time index via full unroll).  Epilogue: shfl_xor(32) g-pair
// combine -> 32KB LDS [wave][j][k] -> 8-way sum -> device atomicAdd to out.
// i-side: direct atomicAdd (one owner per (i,k)).
// Work = 0.52x full pairwise; no P buffer, no K3.
// ---------------------------------------------------------------------------
__global__ __launch_bounds__(512) void k2_sym_pairwise(
    const float* __restrict__ m, float* __restrict__ out) {
  __shared__ float redJ[8][32][32];   // 32 KB

  int b = blockIdx.x;
  int a = 0, rem = b;
  while (rem >= 32 - a) { rem -= 32 - a; ++a; }   // triangular decode
  int c = a + rem;
  bool offd = (a != c);

  int t = threadIdx.x;
  int k = t & 31, g = t >> 5;        // g 0..15
  int w = t >> 6;                    // wave 0..7
  int ia = a * 32 + g * 2;

  const float4* mv = reinterpret_cast<const float4*>(m);  // m[i][c4]: idx = i*64 + c4
  float4 A00 = mv[(size_t)ia * 64 + k * 2];
  float4 A01 = mv[(size_t)ia * 64 + k * 2 + 1];
  float4 A10 = mv[(size_t)(ia + 1) * 64 + k * 2];
  float4 A11 = mv[(size_t)(ia + 1) * 64 + k * 2 + 1];

  float accI0 = 0.f, accI1 = 0.f;
  float accJr[32];
#pragma unroll
  for (int jj = 0; jj < 32; ++jj) {
    int j = c * 32 + jj;
    float4 C0 = mv[(size_t)j * 64 + k * 2];
    float4 C1 = mv[(size_t)j * 64 + k * 2 + 1];
    float s0 = fabsf(A00.x - C0.x) + fabsf(A00.y - C0.y) +
               fabsf(A00.z - C0.z) + fabsf(A00.w - C0.w) +
               fabsf(A01.x - C1.x) + fabsf(A01.y - C1.y) +
               fabsf(A01.z - C1.z) + fabsf(A01.w - C1.w);
    float s1 = fabsf(A10.x - C0.x) + fabsf(A10.y - C0.y) +
               fabsf(A10.z - C0.z) + fabsf(A10.w - C0.w) +
               fabsf(A11.x - C1.x) + fabsf(A11.y - C1.y) +
               fabsf(A11.z - C1.z) + fabsf(A11.w - C1.w);
    float e0 = __expf(-s0);
    float e1 = __expf(-s1);
    accI0 += e0;
    accI1 += e1;
    accJr[jj] = e0 + e1;             // register, compile-time index
  }

  // i-side: unique owner per (row, k) -> device-scope atomicAdd into out
  atomicAdd(&out[(size_t)ia * OUTF + F_SZ + k], accI0);
  atomicAdd(&out[(size_t)(ia + 1) * OUTF + F_SZ + k], accI1);

  if (offd) {
    // combine the wave's two g's: lanes l and l^32 share k
#pragma unroll
    for (int jj = 0; jj < 32; ++jj)
      accJr[jj] += __shfl_xor(accJr[jj], 32);
    if ((t & 63) < 32) {             // lanes 0..31 hold the pair sums
#pragma unroll
      for (int jj = 0; jj < 32; ++jj)
        redJ[w][jj][k] = accJr[jj];  // banks = k: conflict-free
    }
    __syncthreads();
#pragma unroll
    for (int s = 0; s < 2; ++s) {
      int slot = t + s * 512;        // 1024 slots = 32 j x 32 k
      int j = slot >> 5, kk = slot & 31;
      float v = 0.f;
#pragma unroll
      for (int ww = 0; ww < 8; ++ww) v += redJ[ww][j][kk];
      atomicAdd(&out[(size_t)(c * 32 + j) * OUTF + F_SZ + kk], v);
    }
  }
}

extern "C" void kernel_launch(void* const* d_in, const int* in_sizes, int n_in,
                              void* d_out, int out_size, void* d_ws, size_t ws_size,
                              hipStream_t stream) {
  const float* x = (const float*)d_in[0];
  const float* W = (const float*)d_in[1];
  float* out = (float*)d_out;
  float* m = (float*)d_ws;    // 1 MB

  k1_gemm_copy<<<dim3(384), 512, 0, stream>>>(x, W, m, out);
  k2_sym_pairwise<<<dim3(528), 512, 0, stream>>>(m, out);
}